// Round 10
// baseline (263.718 us; speedup 1.0000x reference)
//
#include <hip/hip_runtime.h>
#include <stdint.h>

// ---------------------------------------------------------------------------
// Problem constants
// ---------------------------------------------------------------------------
#define N_PIX   32768      // B*H*W = 8*64*64
#define C_DIM   512
#define K_Q     3072
#define NCLS    4
#define NQ      256
#define N_SAMP  1024       // NCLS*NQ
#define HW      4096       // H*W
#define L_ROW   3073       // 1 + K_Q
#define KH      1024       // stored split-K: [hi(512) | lo(512)]
#define KP      1536       // effective bf16 GEMM K' = 3 terms * 512

typedef float f32x4 __attribute__((ext_vector_type(4)));
typedef short s16x8 __attribute__((ext_vector_type(8)));   // 8 bf16 as shorts

__device__ inline unsigned short f2bf(float f) {           // RNE f32->bf16
  uint32_t u = __float_as_uint(f);
  return (unsigned short)((u + 0x7FFFu + ((u >> 16) & 1u)) >> 16);
}
__device__ inline float bf2f(unsigned short h) {
  return __uint_as_float(((uint32_t)h) << 16);
}

// ---------------------------------------------------------------------------
// Threefry2x32-20 (jax partitionable threefry — VERIFIED R1)
// ---------------------------------------------------------------------------
__host__ __device__ inline void tf2x32(uint32_t k0, uint32_t k1,
                                       uint32_t x0, uint32_t x1,
                                       uint32_t& o0, uint32_t& o1) {
  uint32_t ks2 = k0 ^ k1 ^ 0x1BD11BDAu;
  x0 += k0; x1 += k1;
#define ROTL_(v,d) (((v)<<(d))|((v)>>(32-(d))))
#define RND_(r) { x0 += x1; x1 = ROTL_(x1, r); x1 ^= x0; }
  RND_(13) RND_(15) RND_(26) RND_(6)
  x0 += k1; x1 += ks2 + 1u;
  RND_(17) RND_(29) RND_(16) RND_(24)
  x0 += ks2; x1 += k0 + 2u;
  RND_(13) RND_(15) RND_(26) RND_(6)
  x0 += k0; x1 += k1 + 3u;
  RND_(17) RND_(29) RND_(16) RND_(24)
  x0 += k1; x1 += ks2 + 4u;
  RND_(13) RND_(15) RND_(26) RND_(6)
  x0 += ks2; x1 += k0 + 5u;
  o0 = x0; o1 = x1;
#undef RND_
#undef ROTL_
}

// ---------------------------------------------------------------------------
// K_convq: queue [512][3072] f32 -> B2 [3072][1024] bf16 (B^T {hi|lo}).
// Also zeroes the per-class counters (fused k_zero; stream-ordered before
// k_compact). LDS-tiled transpose, stride 65 -> conflict-free.
// ---------------------------------------------------------------------------
__global__ __launch_bounds__(256) void k_convq(const float* __restrict__ queue,
                                               unsigned short* __restrict__ B2,
                                               int* __restrict__ cnt) {
  if (blockIdx.x == 0 && blockIdx.y == 0 && threadIdx.x < NCLS)
    cnt[threadIdx.x] = 0;
  __shared__ float tile[64][65];
  int tid = threadIdx.x;
  int n0 = blockIdx.x * 64;
  int k0 = blockIdx.y * 64;
#pragma unroll
  for (int it = 0; it < 4; ++it) {
    int r = (tid >> 4) + it * 16;
    int c4 = (tid & 15) * 4;
    float4 v = *(const float4*)(queue + (size_t)(k0 + r) * K_Q + n0 + c4);
    tile[r][c4 + 0] = v.x; tile[r][c4 + 1] = v.y;
    tile[r][c4 + 2] = v.z; tile[r][c4 + 3] = v.w;
  }
  __syncthreads();
  int tn = tid >> 2;
  int kc = (tid & 3) * 16;
  unsigned short* rowp = B2 + (size_t)(n0 + tn) * KH + k0 + kc;
#pragma unroll
  for (int g8 = 0; g8 < 2; ++g8) {
    s16x8 vhi, vlo;
#pragma unroll
    for (int j = 0; j < 8; ++j) {
      float v = tile[kc + g8 * 8 + j][tn];
      unsigned short h = f2bf(v);
      vhi[j] = (short)h;
      vlo[j] = (short)f2bf(v - bf2f(h));
    }
    *(s16x8*)(rowp + g8 * 8)       = vhi;
    *(s16x8*)(rowp + 512 + g8 * 8) = vlo;
  }
}

// ---------------------------------------------------------------------------
// K1: compact valid-pixel lists per class (LDS histogram; fixed in R3)
// ---------------------------------------------------------------------------
__global__ __launch_bounds__(256) void k_compact(const int* __restrict__ target,
                                                 int* __restrict__ cnt,
                                                 int* __restrict__ lists) {
  __shared__ int lcnt[NCLS];
  __shared__ int lbase[NCLS];
  int tid = threadIdx.x;
  if (tid < NCLS) lcnt[tid] = 0;
  __syncthreads();
  int p = blockIdx.x * 256 + tid;
  int c = target[p];
  int lpos = atomicAdd(&lcnt[c], 1);
  __syncthreads();
  if (tid < NCLS) lbase[tid] = atomicAdd(&cnt[tid], lcnt[tid]);
  __syncthreads();
  lists[c * N_PIX + lbase[c] + lpos] = p;
}

// ---------------------------------------------------------------------------
// K2: Gumbel-max sampling == argmax over valid pixels of raw uniform bits.
// ---------------------------------------------------------------------------
__global__ __launch_bounds__(256) void k_sample(
    const int* __restrict__ cnt, const int* __restrict__ lists,
    int* __restrict__ samp,
    uint32_t k0a, uint32_t k0b, uint32_t k1a, uint32_t k1b,
    uint32_t k2a, uint32_t k2b, uint32_t k3a, uint32_t k3b) {
  int c = blockIdx.y;
  int q = blockIdx.x;
  uint32_t ka, kb;
  if      (c == 0) { ka = k0a; kb = k0b; }
  else if (c == 1) { ka = k1a; kb = k1b; }
  else if (c == 2) { ka = k2a; kb = k2b; }
  else             { ka = k3a; kb = k3b; }

  int nv = cnt[c];
  const int* lst = lists + c * N_PIX;
  unsigned long long best = 0ull;
  for (int t = threadIdx.x; t < nv; t += 256) {
    int p = lst[t];
    uint32_t j = (uint32_t)(q * N_PIX + p);
    uint32_t o0, o1;
    tf2x32(ka, kb, 0u, j, o0, o1);
    uint32_t bits = o0 ^ o1;
    unsigned long long v =
        ((unsigned long long)(bits >> 9) << 15) | (unsigned)(32767 - p);
    if (v > best) best = v;
  }
  __shared__ unsigned long long red[256];
  red[threadIdx.x] = best;
  __syncthreads();
  for (int s = 128; s > 0; s >>= 1) {
    if (threadIdx.x < s && red[threadIdx.x + s] > red[threadIdx.x])
      red[threadIdx.x] = red[threadIdx.x + s];
    __syncthreads();
  }
  if (threadIdx.x == 0)
    samp[c * NQ + q] = 32767 - (int)(red[0] & 0x7FFFull);
}

// ---------------------------------------------------------------------------
// K3: shuffle = stable sort by random u32 keys; 16 blocks x 64 threads.
// ---------------------------------------------------------------------------
__global__ __launch_bounds__(64) void k_perm(
    const int* __restrict__ samp, int* __restrict__ idx_final,
    int* __restrict__ labels_shuf, float* __restrict__ out_labels,
    uint32_t sk0, uint32_t sk1) {
  __shared__ uint32_t keys_s[N_SAMP];
  int lt = threadIdx.x;
  for (int t = lt; t < N_SAMP; t += 64) {
    uint32_t o0, o1;
    tf2x32(sk0, sk1, 0u, (uint32_t)t, o0, o1);
    keys_s[t] = o0 ^ o1;
  }
  __syncthreads();
  int i = blockIdx.x * 64 + lt;
  uint32_t ki = keys_s[i];
  int rank = 0;
#pragma unroll 4
  for (int j = 0; j < N_SAMP; ++j) {
    uint32_t kj = keys_s[j];
    rank += (int)((kj < ki) | ((kj == ki) & (j < i)));
  }
  idx_final[rank] = samp[i];
  int lab = i >> 8;
  labels_shuf[rank] = lab;
  out_labels[rank] = (float)lab;
}

// ---------------------------------------------------------------------------
// K4: one wave per pixel; shfl_xor reductions; coalesced s16x8 hi/lo stores.
// (R9: confirmed line-BW-bound ~11 us — both layouts equal; keep this one.)
// ---------------------------------------------------------------------------
__global__ __launch_bounds__(64) void k_gather(
    const float* __restrict__ fs, const float* __restrict__ ft,
    const int* __restrict__ idx_final, unsigned short* __restrict__ A2,
    float* __restrict__ out_logits) {
  int n = blockIdx.x;
  int p = idx_final[n];
  int b = p >> 12;
  int hw = p & (HW - 1);
  const float* fsb = fs + (size_t)b * C_DIM * HW + hw;
  const float* ftb = ft + (size_t)b * C_DIM * HW + hw;
  int lane = threadIdx.x;

  float s[8], t[8];
#pragma unroll
  for (int j = 0; j < 8; ++j) {
    int c = lane * 8 + j;
    s[j] = fsb[(size_t)c * HW];
    t[j] = ftb[(size_t)c * HW];
  }

  float ss = 0.f, tt = 0.f;
#pragma unroll
  for (int j = 0; j < 8; ++j) { ss += s[j] * s[j]; tt += t[j] * t[j]; }
#pragma unroll
  for (int m = 1; m < 64; m <<= 1) {
    ss += __shfl_xor(ss, m);
    tt += __shfl_xor(tt, m);
  }
  float ns = fmaxf(sqrtf(ss), 1e-12f);
  float nt = fmaxf(sqrtf(tt), 1e-12f);

  float st = 0.f;
  s16x8 vhi, vlo;
#pragma unroll
  for (int j = 0; j < 8; ++j) {
    float a = s[j] / ns;
    float bb = t[j] / nt;
    st += a * bb;
    unsigned short h = f2bf(a);
    vhi[j] = (short)h;
    vlo[j] = (short)f2bf(a - bf2f(h));
  }
  unsigned short* row = A2 + (size_t)n * KH;
  *(s16x8*)(row + lane * 8)       = vhi;
  *(s16x8*)(row + 512 + lane * 8) = vlo;

#pragma unroll
  for (int m = 1; m < 64; m <<= 1) st += __shfl_xor(st, m);
  if (lane == 0)
    out_logits[(size_t)n * L_ROW] = st * (1.0f / 0.07f);
}

// ---------------------------------------------------------------------------
// K5 v3 (R10): LDS-FREE direct-fragment GEMM. R9 analysis: the LDS version
// was ds_read-bound (8 ds_read_b128 ~96cy vs 8 MFMA ~40cy per K64 step, + 2
// barriers). With B^T storage the MFMA fragment pattern (row=lane&15,
// k=(lane>>4)*8) is loadable straight from global (16 x 64B segments per
// inst = same line count as ideal coalescing). 1 wave per block, 64x64 out,
// 16 accumulators, 3-buffer 2-chunk-ahead register pipeline, no LDS, no
// barriers. XCD-chunked swizzle (768%8==0) keeps A2 + 6 B-panels L2-resident
// per XCD. Same 48-step K-chain per accumulator => bit-identical to R9.
// ---------------------------------------------------------------------------
__device__ __forceinline__ void gemm_loadc(
    const unsigned short* const (&pA)[4], const unsigned short* const (&pB)[4],
    int sA_, int sB_, s16x8 (&ra)[4], s16x8 (&rb)[4]) {
  ra[0] = *(const s16x8*)(pA[0] + sA_);
  ra[1] = *(const s16x8*)(pA[1] + sA_);
  ra[2] = *(const s16x8*)(pA[2] + sA_);
  ra[3] = *(const s16x8*)(pA[3] + sA_);
  rb[0] = *(const s16x8*)(pB[0] + sB_);
  rb[1] = *(const s16x8*)(pB[1] + sB_);
  rb[2] = *(const s16x8*)(pB[2] + sB_);
  rb[3] = *(const s16x8*)(pB[3] + sB_);
}

__global__ __launch_bounds__(64) void k_gemm(
    const unsigned short* __restrict__ A2,   // [1024][1024] {hi|lo}
    const unsigned short* __restrict__ B2,   // [3072][1024] {hi|lo} (B^T)
    const int* __restrict__ labels,
    const int* __restrict__ qlab,
    float* __restrict__ out) {
  int lane = threadIdx.x;
  // XCD-chunked swizzle: 768 blocks, 8 XCDs -> 96 contiguous logical per XCD
  int bid = (int)blockIdx.x;
  int swz = (bid & 7) * 96 + (bid >> 3);
  int bm = (swz & 15) * 64;                  // 16 m-tiles
  int bn = (swz >> 4) * 64;                  // 48 n-tiles

  int koff = (lane >> 4) * 8;                // k-offset within K32 chunk
  int rsel = lane & 15;                      // row/col within 16-group
  const unsigned short* pA[4];
  const unsigned short* pB[4];
#pragma unroll
  for (int g = 0; g < 4; ++g) {
    pA[g] = A2 + (size_t)(bm + g * 16 + rsel) * KH + koff;
    pB[g] = B2 + (size_t)(bn + g * 16 + rsel) * KH + koff;
  }

  f32x4 acc[4][4] = {};
  s16x8 rA[3][4], rB[3][4];

  // split-term source offsets (u16 units), identical mapping to R7/R9:
  // A' = [Ahi|Ahi|Alo] ; B' = [Bhi|Blo|Bhi] over stored [hi(512)|lo(512)]
#define SAOF(kp) (((kp) < 512) ? (kp) : (kp) - 512)
#define SBOF(kp) (((kp) < 1024) ? (kp) : (kp) - 1024)

  gemm_loadc(pA, pB, SAOF(0),  SBOF(0),  rA[0], rB[0]);
  gemm_loadc(pA, pB, SAOF(32), SBOF(32), rA[1], rB[1]);

#pragma unroll
  for (int c = 0; c < 48; ++c) {             // K32 chunks, kp = c*32 (same
    if (c + 2 < 48) {                        //  K order as R9 => bit-identical)
      int kp2 = (c + 2) * 32;
      gemm_loadc(pA, pB, SAOF(kp2), SBOF(kp2), rA[(c + 2) % 3], rB[(c + 2) % 3]);
    }
    int buf = c % 3;
#pragma unroll
    for (int mi = 0; mi < 4; ++mi)
#pragma unroll
      for (int ni = 0; ni < 4; ++ni)
        acc[mi][ni] = __builtin_amdgcn_mfma_f32_16x16x32_bf16(
            rA[buf][mi], rB[buf][ni], acc[mi][ni], 0, 0, 0);
  }
#undef SAOF
#undef SBOF

  float* out_mask = out + (size_t)N_SAMP * L_ROW;
  const float sc = 1.0f / 0.07f;
#pragma unroll
  for (int mi = 0; mi < 4; ++mi) {
#pragma unroll
    for (int ni = 0; ni < 4; ++ni) {
#pragma unroll
      for (int j = 0; j < 4; ++j) {
        int rl = mi * 16 + ((lane >> 4) << 2) + j;   // C row (m89 layout)
        int cl = ni * 16 + (lane & 15);              // C col
        int row = bm + rl, col = bn + cl;
        out[(size_t)row * L_ROW + 1 + col] = acc[mi][ni][j] * sc;
        out_mask[(size_t)row * K_Q + col] =
            (labels[row] == qlab[col]) ? 1.0f : 0.0f;
      }
    }
  }
}

// ---------------------------------------------------------------------------
// Launch — 6 dispatches. A2/B2 in ws (ws_size = 256 MiB, verified R6).
// ---------------------------------------------------------------------------
extern "C" void kernel_launch(void* const* d_in, const int* in_sizes, int n_in,
                              void* d_out, int out_size, void* d_ws, size_t ws_size,
                              hipStream_t stream) {
  const float* fs     = (const float*)d_in[1];
  const float* ft     = (const float*)d_in[2];
  const int*   target = (const int*)d_in[3];
  const float* queue  = (const float*)d_in[4];
  const int*   qlab   = (const int*)d_in[5];
  float* out = (float*)d_out;

  // ws layout (~10.3 MB of the 256 MiB)
  char* ws = (char*)d_ws;
  int* cnt   = (int*)(ws + 0);
  int* samp  = (int*)(ws + 4096);
  int* idxf  = (int*)(ws + 8192);
  int* labs  = (int*)(ws + 12288);
  int* lists = (int*)(ws + 16384);                          // 512 KB
  unsigned short* A2 = (unsigned short*)(ws + (1u << 20));  // 2 MB @ 1 MiB
  unsigned short* B2 = (unsigned short*)(ws + (4u << 20));  // 6.29 MB @ 4 MiB

  // host-side RNG key derivation (partitionable threefry — verified R1)
  uint32_t ck[5][2];
  for (int i = 0; i < 5; ++i)
    tf2x32(0u, 42u, 0u, (uint32_t)i, ck[i][0], ck[i][1]);
  uint32_t sk0, sk1;
  tf2x32(ck[4][0], ck[4][1], 0u, 1u, sk0, sk1);

  float* out_labels = out + (size_t)N_SAMP * L_ROW + (size_t)N_SAMP * K_Q;

  k_convq<<<dim3(K_Q / 64, C_DIM / 64), 256, 0, stream>>>(queue, B2, cnt);
  k_compact<<<N_PIX / 256, 256, 0, stream>>>(target, cnt, lists);
  k_sample<<<dim3(NQ, NCLS), 256, 0, stream>>>(
      cnt, lists, samp,
      ck[0][0], ck[0][1], ck[1][0], ck[1][1],
      ck[2][0], ck[2][1], ck[3][0], ck[3][1]);
  k_perm<<<16, 64, 0, stream>>>(samp, idxf, labs, out_labels, sk0, sk1);
  k_gather<<<N_SAMP, 64, 0, stream>>>(fs, ft, idxf, A2, out);
  k_gemm<<<768, 64, 0, stream>>>(A2, B2, labs, qlab, out);
}